// Round 1
// 326.411 us; speedup vs baseline: 1.0241x; 1.0241x over previous
//
#include <hip/hip_runtime.h>

#define D_IN   256
#define HID    256
#define NNODES 100000
#define NEDGE  262144
#define NGROUPS 6250        // 100000 / 16 rows per MFMA m-group (exact)
#define GBLK   128          // blocks per z (x2 z = 256 blocks = 1/CU)
#define GW     16           // waves per block (1024 threads)

typedef short short8            __attribute__((ext_vector_type(8)));
typedef float float4v           __attribute__((ext_vector_type(4)));
typedef unsigned short ushort8  __attribute__((ext_vector_type(8)));

__device__ __forceinline__ unsigned short f32_to_bf16_rne(float f) {
    unsigned int u = __float_as_uint(f);
    unsigned int r = u + 0x7FFFu + ((u >> 16) & 1u);
    return (unsigned short)(r >> 16);
}
__device__ __forceinline__ float bf16_to_f32(unsigned short h) {
    return __uint_as_float(((unsigned int)h) << 16);
}

// -------- W1 (fp32 [2*256][256], k-major) -> Wt (bf16 [z][n][k]) — LDS tile transpose --------
__global__ __launch_bounds__(256) void convert_w(
    const float* __restrict__ W1, unsigned short* __restrict__ Wt)
{
    __shared__ float tile[64][65];
    const int z = blockIdx.z, kb = blockIdx.x * 64, nb = blockIdx.y * 64;
    const int t = threadIdx.x;
    const int g = t >> 6, c = t & 63;
#pragma unroll
    for (int r = 0; r < 16; r++) {
        int kl = g * 16 + r;
        tile[kl][c] = W1[((size_t)(z * 256 + kb + kl)) * 256 + nb + c];
    }
    __syncthreads();
#pragma unroll
    for (int r = 0; r < 16; r++) {
        int nl = g * 16 + r;
        Wt[((size_t)(z * 256 + nb + nl)) * 256 + kb + c] = f32_to_bf16_rne(tile[c][nl]);
    }
}

// -------- Phase 1: U = Xsrc@W1_top + b1 (bf16), V = Xdst@W1_bot (bf16) --------
// Round-4 structure: B (256x256 bf16 = 128 KiB) resident in LDS, XOR-swizzled
// (chunk ^= n&7) for conflict-free ds_read_b128. ONE barrier per kernel; 16
// independent waves/CU each stream 16-row A groups global->reg (fragment-order,
// coalesced 16x128B), convert fp32->bf16 in-reg, swapped-operand MFMA
// (mfma(B,A) => C^T) so each lane owns one output ROW -> direct 8B row stores,
// no LDS epilogue. No K-loop barriers at all (the old structure's 8 barrier
// drains per block were the 112us: MfmaUtil 9%, all pipes idle).
__global__ __launch_bounds__(1024, 4) void gemm_xw_mfma(
    const float* __restrict__ Xsrc, const float* __restrict__ Xdst,
    const unsigned short* __restrict__ Wt, const float* __restrict__ b1,
    unsigned short* __restrict__ U, unsigned short* __restrict__ V)
{
    const int zz = blockIdx.z;
    const float* X = zz ? Xdst : Xsrc;
    const unsigned short* Wz = Wt + (size_t)zz * 256 * 256;
    unsigned short* C = zz ? V : U;

    __shared__ __align__(16) unsigned short Bs[256 * 256];   // 128 KiB

    const int t = threadIdx.x;
    // Stage B once: 8192 16B-chunks / 1024 threads = 8 each. Global read
    // coalesced (32 consecutive threads = 512B of one row); LDS write swizzled.
#pragma unroll
    for (int i = 0; i < 8; i++) {
        int s = t + (i << 10);
        int n = s >> 5, c = s & 31;
        *(int4*)(Bs + n * 256 + ((c ^ (n & 7)) << 3)) =
            *(const int4*)(Wz + (size_t)n * 256 + (c << 3));
    }
    __syncthreads();        // the only barrier in this kernel

    const int w = t >> 6, lane = t & 63;
    const int quad = lane >> 4, l16 = lane & 15;
    const int r7 = l16 & 7;
    const unsigned short* Bl = Bs + l16 * 256;

    // wave-major wid: the 106 remainder groups land on wave 0 of 106 distinct
    // CUs (max +1 group per CU) instead of piling 4-group waves onto 7 CUs.
    const int wid = w * GBLK + blockIdx.x;

    for (int g = wid; g < NGROUPS; g += GBLK * GW) {
        const int row = (g << 4) + l16;
        const float* Ap = X + (size_t)row * D_IN + (quad << 3);

        float4v acc[16];
#pragma unroll
        for (int i = 0; i < 16; i++) acc[i] = (float4v){0.f, 0.f, 0.f, 0.f};

        // A fragment for (kk): lane holds X[row][kk*32 + quad*8 .. +8] = 2 float4.
        float4 a0 = *(const float4*)(Ap);
        float4 a1 = *(const float4*)(Ap + 4);

#pragma unroll 1            // keep pressure low: 1-deep prefetch, no mass hoist
        for (int kk = 0; kk < 8; kk++) {
            float4 p0 = a0, p1 = a1;
            if (kk < 7) {
                p0 = *(const float4*)(Ap + (kk + 1) * 32);
                p1 = *(const float4*)(Ap + (kk + 1) * 32 + 4);
            }
            short8 af;
            af[0] = (short)f32_to_bf16_rne(a0.x);
            af[1] = (short)f32_to_bf16_rne(a0.y);
            af[2] = (short)f32_to_bf16_rne(a0.z);
            af[3] = (short)f32_to_bf16_rne(a0.w);
            af[4] = (short)f32_to_bf16_rne(a1.x);
            af[5] = (short)f32_to_bf16_rne(a1.y);
            af[6] = (short)f32_to_bf16_rne(a1.z);
            af[7] = (short)f32_to_bf16_rne(a1.w);

            // swizzled chunk offset: logical chunk (4kk+quad) ^ (n&7), n&7 == l16&7
            const int cs = (((kk << 2) + quad) ^ r7) << 3;
#pragma unroll
            for (int tt = 0; tt < 16; tt++) {
                short8 bf = *(const short8*)(Bl + tt * 4096 + cs);
                // swapped operands: D = (Wt-tile) x (X-tile) = C^T slice:
                // lane owns col m=l16 (one row of C), rows n = tt*16+quad*4+r
                acc[tt] = __builtin_amdgcn_mfma_f32_16x16x32_bf16(bf, af, acc[tt], 0, 0, 0);
            }
            a0 = p0; a1 = p1;
        }

        // Epilogue: lane writes its own row: 16 x 8B stores; the 4 quads of a
        // row cover 32B contiguous per tt; L2 write-combines across tt.
        unsigned short* Crow = C + (size_t)row * HID + (quad << 2);
#pragma unroll
        for (int tt = 0; tt < 16; tt++) {
            float4v a = acc[tt];
            if (zz == 0) {
                float4 bb = *(const float4*)(b1 + tt * 16 + (quad << 2));
                a[0] += bb.x; a[1] += bb.y; a[2] += bb.z; a[3] += bb.w;
            }
            ushort4 pk;
            pk.x = f32_to_bf16_rne(a[0]);
            pk.y = f32_to_bf16_rne(a[1]);
            pk.z = f32_to_bf16_rne(a[2]);
            pk.w = f32_to_bf16_rne(a[3]);
            *(ushort4*)(Crow + tt * 16) = pk;
        }
    }
}

// -------- Phase 2: out[e] = relu(U[s]+V[d]) . W2 + b2   (b1 folded into U) --------
// 16 edges per wave, half-wave pairing: lanes 0-31 own edge 2p, lanes 32-63 own
// edge 2p+1. Each row gather is ONE 1 KB wave-load (16 B/lane). All 16 gathers
// issued before any reduction; 5-level xor-shuffle per edge pair.
__global__ __launch_bounds__(256) void edge_score_bf16(
    const unsigned short* __restrict__ U, const unsigned short* __restrict__ V,
    const float* __restrict__ W2, const float* __restrict__ b2,
    const int* __restrict__ epos, const int* __restrict__ eneg,
    float* __restrict__ out)
{
    const int w = threadIdx.x >> 6, lane = threadIdx.x & 63;
    const int half = lane >> 5, hl = lane & 31;
    const int ebase = blockIdx.x * 64 + w * 16;     // 16 edges per wave

    const int* ei = (ebase < NEDGE) ? epos : eneg;
    const int eb2 = (ebase < NEDGE) ? ebase : ebase - NEDGE;

    int sidx[8], didx[8];
#pragma unroll
    for (int p = 0; p < 8; p++) {
        int e = eb2 + 2 * p + half;
        sidx[p] = ei[e];
        didx[p] = ei[NEDGE + e];
    }
    ushort8 uu[8], vv[8];
#pragma unroll
    for (int p = 0; p < 8; p++)
        uu[p] = *(const ushort8*)(U + (size_t)sidx[p] * HID + hl * 8);
#pragma unroll
    for (int p = 0; p < 8; p++)
        vv[p] = *(const ushort8*)(V + (size_t)didx[p] * HID + hl * 8);

    float w2r[8];
    *(float4*)&w2r[0] = *(const float4*)(W2 + hl * 8);
    *(float4*)&w2r[4] = *(const float4*)(W2 + hl * 8 + 4);
    const float bb2 = b2[0];

#pragma unroll
    for (int p = 0; p < 8; p++) {
        float s = 0.f;
#pragma unroll
        for (int q = 0; q < 8; q++)
            s += fmaxf(bf16_to_f32(uu[p][q]) + bf16_to_f32(vv[p][q]), 0.f) * w2r[q];
#pragma unroll
        for (int off = 16; off; off >>= 1)     // xor within each 32-lane half
            s += __shfl_xor(s, off, 64);
        if (hl == 0) out[ebase + 2 * p + half] = s + bb2;
    }
}

// -------- Fallback (ws too small): direct per-edge MLP --------
__global__ __launch_bounds__(256) void edge_score_direct(
    const float* __restrict__ xs_, const float* __restrict__ xd_,
    const float* __restrict__ W1, const float* __restrict__ b1,
    const float* __restrict__ W2, const float* __restrict__ b2,
    const int* __restrict__ epos, const int* __restrict__ eneg,
    float* __restrict__ out)
{
    __shared__ float xrow[2 * D_IN];
    __shared__ float red[256];
    const int e = blockIdx.x;
    const int* ei = (e < NEDGE) ? epos : eneg;
    const int e2  = (e < NEDGE) ? e : e - NEDGE;
    const int s = ei[e2];
    const int d = ei[NEDGE + e2];
    const int t = threadIdx.x;

    xrow[t]        = xs_[(size_t)s * D_IN + t];
    xrow[D_IN + t] = xd_[(size_t)d * D_IN + t];
    __syncthreads();

    float acc = b1[t];
    for (int k = 0; k < 2 * D_IN; k++)
        acc += xrow[k] * W1[(size_t)k * HID + t];
    acc = fmaxf(acc, 0.f);
    red[t] = acc * W2[t];
    __syncthreads();
    for (int st = 128; st; st >>= 1) {
        if (t < st) red[t] += red[t + st];
        __syncthreads();
    }
    if (t == 0) out[e] = red[0] + b2[0];
}

extern "C" void kernel_launch(void* const* d_in, const int* in_sizes, int n_in,
                              void* d_out, int out_size, void* d_ws, size_t ws_size,
                              hipStream_t stream) {
    const float* x_src = (const float*)d_in[0];
    const float* x_dst = (const float*)d_in[1];
    const float* W1    = (const float*)d_in[2];
    const float* b1    = (const float*)d_in[3];
    const float* W2    = (const float*)d_in[4];
    const float* b2    = (const float*)d_in[5];
    const int*   epos  = (const int*)d_in[6];
    const int*   eneg  = (const int*)d_in[7];
    float* out = (float*)d_out;

    const size_t uv   = (size_t)NNODES * HID;
    const size_t need = (2 * uv + 2 * 256 * 256) * sizeof(unsigned short);
    if (ws_size >= need) {
        unsigned short* U  = (unsigned short*)d_ws;
        unsigned short* V  = U + uv;
        unsigned short* Wt = V + uv;
        convert_w<<<dim3(4, 4, 2), 256, 0, stream>>>(W1, Wt);
        gemm_xw_mfma<<<dim3(GBLK, 1, 2), 1024, 0, stream>>>(x_src, x_dst, Wt, b1, U, V);
        edge_score_bf16<<<(2 * NEDGE) / 64, 256, 0, stream>>>(U, V, W2, b2, epos, eneg, out);
    } else {
        edge_score_direct<<<2 * NEDGE, 256, 0, stream>>>(x_src, x_dst, W1, b1, W2, b2, epos, eneg, out);
    }
}